// Round 3
// baseline (573.635 us; speedup 1.0000x reference)
//
#include <hip/hip_runtime.h>

typedef unsigned short u16;
typedef short bf16x8 __attribute__((ext_vector_type(8)));
typedef float f32x4 __attribute__((ext_vector_type(4)));

__device__ __forceinline__ u16 f2bf(float f) {
  union { float f; unsigned u; } x; x.f = f;
  unsigned r = x.u + 0x7FFFu + ((x.u >> 16) & 1u);
  return (u16)(r >> 16);
}

// ---------------------------------------------------------------- weights ---
// out[n*K + k] = bf16(in[k*N + n])   (K x N fp32  ->  N x K bf16)
__global__ void tconv(const float* __restrict__ in, u16* __restrict__ out, int K, int N) {
  int idx = blockIdx.x * 256 + threadIdx.x;
  if (idx >= K * N) return;
  int n = idx / K, k2 = idx - n * K;
  out[idx] = f2bf(in[(size_t)k2 * N + n]);
}

// ------------------------------------------------------- LN1+shift+window ---
__global__ __launch_bounds__(256)
void ln1_win(const float* __restrict__ x1, const float* __restrict__ x2,
             const float* __restrict__ x3, const float* __restrict__ g,
             const float* __restrict__ bb, u16* __restrict__ o1,
             u16* __restrict__ o2, u16* __restrict__ o3) {
  const int t = blockIdx.x * 4 + (threadIdx.x >> 6);
  const int lane = threadIdx.x & 63;
  const int win = t / 49, i = t - win * 49;
  const int b = win >> 6, wi = win & 63;
  const int ih = i / 7, iw = i - ih * 7;
  int h2 = (wi >> 3) * 7 + ih + 3; if (h2 >= 56) h2 -= 56;
  int w2 = (wi & 7) * 7 + iw + 3; if (w2 >= 56) w2 -= 56;
  const size_t src = ((size_t)b * 3136 + (size_t)h2 * 56 + w2) * 256 + lane * 4;
  const size_t dst = (size_t)t * 256 + lane * 4;
  const float4 gv = *(const float4*)(g + lane * 4);
  const float4 bv = *(const float4*)(bb + lane * 4);
  const float* xs[3] = {x1, x2, x3};
  u16* os[3] = {o1, o2, o3};
#pragma unroll
  for (int s = 0; s < 3; ++s) {
    float4 v = *(const float4*)(xs[s] + src);
    float sm = v.x + v.y + v.z + v.w;
    float s2 = v.x * v.x + v.y * v.y + v.z * v.z + v.w * v.w;
#pragma unroll
    for (int off = 32; off > 0; off >>= 1) {
      sm += __shfl_down(sm, off);
      s2 += __shfl_down(s2, off);
    }
    sm = __shfl(sm, 0); s2 = __shfl(s2, 0);
    float mean = sm * (1.f / 256.f);
    float rstd = rsqrtf(s2 * (1.f / 256.f) - mean * mean + 1e-5f);
    ushort4 o;
    o.x = f2bf((v.x - mean) * rstd * gv.x + bv.x);
    o.y = f2bf((v.y - mean) * rstd * gv.y + bv.y);
    o.z = f2bf((v.z - mean) * rstd * gv.z + bv.z);
    o.w = f2bf((v.w - mean) * rstd * gv.w + bv.w);
    *(ushort4*)(os[s] + dst) = o;
  }
}

// ------------------------------------------------------------------ GEMM ----
#define BM 128
#define BN 128
#define BK 64

template <int EPI>
__global__ __launch_bounds__(256, 2)
void gemm_nt(const u16* __restrict__ A, const u16* __restrict__ Bt,
             const float* __restrict__ bias, float alpha, int M, int N, int K,
             void* __restrict__ out_, const float* __restrict__ res) {
  __shared__ u16 As[2][BM * BK];
  __shared__ u16 Bs[2][BN * BK];
  const int tid = threadIdx.x;
  const int lane = tid & 63;
  const int wave = tid >> 6;
  const int wm = wave >> 1, wn = wave & 1;
  const long tM = (long)blockIdx.x * BM, tN = (long)blockIdx.y * BN;

  f32x4 acc[4][4] = {};

  auto stage = [&](u16* dst, const u16* src, long rowBase, int ld, int kOff) {
#pragma unroll
    for (int it = 0; it < 4; ++it) {
      int gi = it * 256 + tid;
      int row = gi >> 3, gl = gi & 7;
      int gs = gl ^ (row & 7);
      uint4 vv = *(const uint4*)(src + (size_t)(rowBase + row) * ld + kOff + gs * 8);
      *(uint4*)(dst + row * BK + gl * 8) = vv;
    }
  };

  stage(As[0], A, tM, K, 0);
  stage(Bs[0], Bt, tN, K, 0);
  __syncthreads();

  const int nkt = K / BK;
  for (int kt = 0; kt < nkt; ++kt) {
    const int cur = kt & 1;
    if (kt + 1 < nkt) {
      stage(As[cur ^ 1], A, tM, K, (kt + 1) * BK);
      stage(Bs[cur ^ 1], Bt, tN, K, (kt + 1) * BK);
    }
#pragma unroll
    for (int kk = 0; kk < BK; kk += 32) {
      bf16x8 af[4], bfv[4];
#pragma unroll
      for (int m = 0; m < 4; ++m) {
        int row = wm * 64 + m * 16 + (lane & 15);
        int g = (kk >> 3) + (lane >> 4);
        af[m] = *(const bf16x8*)&As[cur][row * BK + ((g ^ (row & 7)) << 3)];
      }
#pragma unroll
      for (int n = 0; n < 4; ++n) {
        int col = wn * 64 + n * 16 + (lane & 15);
        int g = (kk >> 3) + (lane >> 4);
        bfv[n] = *(const bf16x8*)&Bs[cur][col * BK + ((g ^ (col & 7)) << 3)];
      }
#pragma unroll
      for (int m = 0; m < 4; ++m)
#pragma unroll
        for (int n = 0; n < 4; ++n)
          acc[m][n] = __builtin_amdgcn_mfma_f32_16x16x32_bf16(af[m], bfv[n], acc[m][n], 0, 0, 0);
    }
    __syncthreads();
  }

#pragma unroll
  for (int m = 0; m < 4; ++m) {
#pragma unroll
    for (int r = 0; r < 4; ++r) {
      const long row = tM + wm * 64 + m * 16 + (lane >> 4) * 4 + r;
      if constexpr (EPI == 2) {
        int win = (int)(row / 49), i = (int)(row - (long)win * 49);
        int b = win >> 6, wi = win & 63;
        int ih = i / 7, iw = i - ih * 7;
        int h2 = (wi >> 3) * 7 + ih + 3; if (h2 >= 56) h2 -= 56;
        int w2 = (wi & 7) * 7 + iw + 3; if (w2 >= 56) w2 -= 56;
        size_t obase = ((size_t)b * 3136 + (size_t)h2 * 56 + w2) * 256;
        float* out = (float*)out_;
#pragma unroll
        for (int n = 0; n < 4; ++n) {
          int col = (int)tN + wn * 64 + n * 16 + (lane & 15);
          out[obase + col] = res[obase + col] + acc[m][n][r] + bias[col];
        }
      } else if constexpr (EPI == 3) {
        float* out = (float*)out_;
#pragma unroll
        for (int n = 0; n < 4; ++n) {
          int col = (int)tN + wn * 64 + n * 16 + (lane & 15);
          size_t oi = (size_t)row * N + col;
          out[oi] = res[oi] + acc[m][n][r] + bias[col];
        }
      } else {
        u16* out = (u16*)out_;
#pragma unroll
        for (int n = 0; n < 4; ++n) {
          int col = (int)tN + wn * 64 + n * 16 + (lane & 15);
          float vv = acc[m][n][r] + bias[col];
          if constexpr (EPI == 0) vv *= alpha;
          else vv = 0.5f * vv * (1.f + erff(vv * 0.70710678118654752f));
          out[(size_t)row * N + col] = f2bf(vv);
        }
      }
    }
  }
}

// ------------------------------------------------- combined attn bias prep --
__global__ __launch_bounds__(256)
void bias_prep(const float* __restrict__ rel, const float* __restrict__ mask,
               float* __restrict__ Bp) {
  const int blk = blockIdx.x;  // 0..511
  const int wi = blk >> 3, h = blk & 7;
  const float* mrow = mask + (size_t)wi * 2401;
  float* o = Bp + (size_t)blk * 4096;
#pragma unroll
  for (int e = 0; e < 16; ++e) {
    int pos = e * 256 + threadIdx.x;
    int r = pos & 3, lane = (pos >> 2) & 63, mini = pos >> 8;
    int mi = mini >> 2, ni = mini & 3;
    int row = mi * 16 + (lane >> 4) * 4 + r;
    int col = ni * 16 + (lane & 15);
    float val;
    if (col >= 49) val = -1e30f;
    else if (row >= 49) val = 0.f;
    else {
      int idx = (row / 7 - col / 7 + 6) * 13 + (row % 7 - col % 7 + 6);
      val = rel[idx * 8 + h] + mrow[row * 49 + col];
    }
    o[pos] = val;
  }
}

// ------------------------------------------------------- MFMA attention -----
__global__ __launch_bounds__(64)
void attn_mfma(const u16* __restrict__ q, const u16* __restrict__ k,
               const u16* __restrict__ v, const float* __restrict__ Bp,
               u16* __restrict__ out) {
  __shared__ u16 Pl[64 * 64];
  __shared__ u16 VT[32 * 64];
  const int lane = threadIdx.x;
  const int unit = blockIdx.x;
  const int win = unit >> 3, head = unit & 7;
  const size_t base = (size_t)win * 49 * 256 + head * 32;

  {
    const int key = lane;
    const u16* vp = v + base + (size_t)key * 256;
#pragma unroll
    for (int p = 0; p < 4; ++p) {
      bf16x8 vv = {};
      if (key < 49) vv = *(const bf16x8*)(vp + p * 8);
#pragma unroll
      for (int e = 0; e < 8; ++e) {
        int dim = p * 8 + e;
        int sw = (dim ^ (dim >> 3)) & 7;
        VT[dim * 64 + ((((key >> 3) ^ sw) << 3) | (key & 7))] = (u16)vv[e];
      }
    }
  }

  const f32x4* bp = (const f32x4*)(Bp + (size_t)((win & 63) * 8 + head) * 4096);
  f32x4 acc[4][4];
#pragma unroll
  for (int mi = 0; mi < 4; ++mi)
#pragma unroll
    for (int ni = 0; ni < 4; ++ni)
      acc[mi][ni] = bp[(mi * 4 + ni) * 64 + lane];

  bf16x8 qf[4], kf[4];
#pragma unroll
  for (int mi = 0; mi < 4; ++mi)
    qf[mi] = *(const bf16x8*)(q + base + (size_t)(mi * 16 + (lane & 15)) * 256 + (lane >> 4) * 8);
#pragma unroll
  for (int ni = 0; ni < 4; ++ni)
    kf[ni] = *(const bf16x8*)(k + base + (size_t)(ni * 16 + (lane & 15)) * 256 + (lane >> 4) * 8);

#pragma unroll
  for (int mi = 0; mi < 4; ++mi)
#pragma unroll
    for (int ni = 0; ni < 4; ++ni)
      acc[mi][ni] = __builtin_amdgcn_mfma_f32_16x16x32_bf16(qf[mi], kf[ni], acc[mi][ni], 0, 0, 0);

  float rinv[4][4];
#pragma unroll
  for (int mi = 0; mi < 4; ++mi) {
#pragma unroll
    for (int r = 0; r < 4; ++r) {
      float mx = fmaxf(fmaxf(acc[mi][0][r], acc[mi][1][r]),
                       fmaxf(acc[mi][2][r], acc[mi][3][r]));
#pragma unroll
      for (int off = 1; off < 16; off <<= 1) mx = fmaxf(mx, __shfl_xor(mx, off));
      float s = 0.f;
#pragma unroll
      for (int ni = 0; ni < 4; ++ni) {
        float e = __expf(acc[mi][ni][r] - mx);
        acc[mi][ni][r] = e;
        s += e;
      }
#pragma unroll
      for (int off = 1; off < 16; off <<= 1) s += __shfl_xor(s, off);
      rinv[mi][r] = 1.f / s;
    }
  }

#pragma unroll
  for (int mi = 0; mi < 4; ++mi)
#pragma unroll
    for (int ni = 0; ni < 4; ++ni)
#pragma unroll
      for (int r = 0; r < 4; ++r) {
        int row = mi * 16 + (lane >> 4) * 4 + r;
        int col = ni * 16 + (lane & 15);
        int sw = (row ^ (row >> 3)) & 7;
        Pl[row * 64 + ((((col >> 3) ^ sw) << 3) | (col & 7))] = f2bf(acc[mi][ni][r]);
      }

  f32x4 acc2[4][2] = {};
#pragma unroll
  for (int ks = 0; ks < 2; ++ks) {
    bf16x8 pa[4], vb[2];
#pragma unroll
    for (int mi = 0; mi < 4; ++mi) {
      int row = mi * 16 + (lane & 15);
      int sw = (row ^ (row >> 3)) & 7;
      pa[mi] = *(const bf16x8*)&Pl[row * 64 + (((ks * 4 + (lane >> 4)) ^ sw) << 3)];
    }
#pragma unroll
    for (int n2 = 0; n2 < 2; ++n2) {
      int dim = n2 * 16 + (lane & 15);
      int sw = (dim ^ (dim >> 3)) & 7;
      vb[n2] = *(const bf16x8*)&VT[dim * 64 + (((ks * 4 + (lane >> 4)) ^ sw) << 3)];
    }
#pragma unroll
    for (int mi = 0; mi < 4; ++mi)
#pragma unroll
      for (int n2 = 0; n2 < 2; ++n2)
        acc2[mi][n2] = __builtin_amdgcn_mfma_f32_16x16x32_bf16(pa[mi], vb[n2], acc2[mi][n2], 0, 0, 0);
  }

#pragma unroll
  for (int mi = 0; mi < 4; ++mi)
#pragma unroll
    for (int r = 0; r < 4; ++r) {
      int row = mi * 16 + (lane >> 4) * 4 + r;
      if (row < 49) {
        float rv = rinv[mi][r];
#pragma unroll
        for (int n2 = 0; n2 < 2; ++n2) {
          int col = n2 * 16 + (lane & 15);
          out[base + (size_t)row * 256 + col] = f2bf(acc2[mi][n2][r] * rv);
        }
      }
    }
}

// ----------------------------------------------------------- fused MLP ------
// One kernel: LN2 + fc1 + GELU + fc2 + residual.  Grid 392 x 128 tokens.
// Dynamic LDS 160 KB: Al (128x256 bf16 LN output), Bl (64 KB weight chunk,
// reused for fw1t chunk then fw2t slice), S1l (128x128 bf16 gelu output).
// Full K fits in LDS -> no K-loop staging; weights are L2-resident.
__global__ __launch_bounds__(256, 1)
void mlp_fused(const float* __restrict__ xmid, const float* __restrict__ g2,
               const float* __restrict__ bb2, const u16* __restrict__ fw1t,
               const float* __restrict__ fb1, const u16* __restrict__ fw2t,
               const float* __restrict__ fb2, float* __restrict__ out) {
  extern __shared__ u16 smem[];
  u16* Al = smem;                 // 128 x 256
  u16* Bl = smem + 128 * 256;     // G1: 128x256 ; G2: 256x128
  u16* S1l = smem + 2 * 128 * 256;  // 128 x 128
  const int tid = threadIdx.x;
  const int lane = tid & 63, wave = tid >> 6;
  const int wm = wave >> 1, wn = wave & 1;
  const long rowBase = (long)blockIdx.x * 128;

  // ---- LN2 phase: 4 rows per pass (wave w -> row p*4+w), 32 passes ----
  {
    const float4 gv = *(const float4*)(g2 + lane * 4);
    const float4 bv = *(const float4*)(bb2 + lane * 4);
    for (int p = 0; p < 32; ++p) {
      int row = p * 4 + wave;
      float4 v = *(const float4*)(xmid + (rowBase + row) * 256 + lane * 4);
      float sm = v.x + v.y + v.z + v.w;
      float s2 = v.x * v.x + v.y * v.y + v.z * v.z + v.w * v.w;
#pragma unroll
      for (int d = 32; d > 0; d >>= 1) {
        sm += __shfl_xor(sm, d);
        s2 += __shfl_xor(s2, d);
      }
      float mean = sm * (1.f / 256.f);
      float rstd = rsqrtf(s2 * (1.f / 256.f) - mean * mean + 1e-5f);
      ushort4 ov;
      ov.x = f2bf((v.x - mean) * rstd * gv.x + bv.x);
      ov.y = f2bf((v.y - mean) * rstd * gv.y + bv.y);
      ov.z = f2bf((v.z - mean) * rstd * gv.z + bv.z);
      ov.w = f2bf((v.w - mean) * rstd * gv.w + bv.w);
      int g = lane >> 1;
      int gs = (g & ~7) | ((g & 7) ^ (row & 7));
      *(ushort4*)(Al + row * 256 + gs * 8 + (lane & 1) * 4) = ov;
    }
  }

  f32x4 accO[4][8] = {};  // per-wave 64 x 128 of the 128x256 output tile

  for (int c = 0; c < 8; ++c) {
    // ---- stage B1 = fw1t rows [c*128, c*128+128), all 256 cols ----
    {
      const u16* src = fw1t + (size_t)c * 128 * 256;
#pragma unroll
      for (int it = 0; it < 16; ++it) {
        int G = it * 256 + tid;  // granule id, 4096 total
        int row = G >> 5, g = G & 31;
        uint4 vv = *(const uint4*)(src + row * 256 + g * 8);
        int gs = (g & ~7) | ((g & 7) ^ (row & 7));
        *(uint4*)(Bl + row * 256 + gs * 8) = vv;
      }
    }
    __syncthreads();

    // ---- G1: S1(128x128) = A @ B1^T ; wave quadrant 64x64 ----
    f32x4 acc1[4][4] = {};
#pragma unroll
    for (int kk = 0; kk < 8; ++kk) {
      bf16x8 af[4], bfv[4];
      int gb = kk * 4 + (lane >> 4);
#pragma unroll
      for (int mi = 0; mi < 4; ++mi) {
        int row = wm * 64 + mi * 16 + (lane & 15);
        int gs = (gb & ~7) | ((gb & 7) ^ (row & 7));
        af[mi] = *(const bf16x8*)&Al[row * 256 + gs * 8];
      }
#pragma unroll
      for (int ni = 0; ni < 4; ++ni) {
        int row = wn * 64 + ni * 16 + (lane & 15);
        int gs = (gb & ~7) | ((gb & 7) ^ (row & 7));
        bfv[ni] = *(const bf16x8*)&Bl[row * 256 + gs * 8];
      }
#pragma unroll
      for (int mi = 0; mi < 4; ++mi)
#pragma unroll
        for (int ni = 0; ni < 4; ++ni)
          acc1[mi][ni] = __builtin_amdgcn_mfma_f32_16x16x32_bf16(af[mi], bfv[ni], acc1[mi][ni], 0, 0, 0);
    }

    // ---- bias + GELU -> S1l (bf16, swizzled) ----
#pragma unroll
    for (int ni = 0; ni < 4; ++ni) {
      int hcol = wn * 64 + ni * 16 + (lane & 15);
      float b1 = fb1[c * 128 + hcol];
      int g = hcol >> 3;
#pragma unroll
      for (int mi = 0; mi < 4; ++mi) {
#pragma unroll
        for (int r = 0; r < 4; ++r) {
          int row = wm * 64 + mi * 16 + (lane >> 4) * 4 + r;
          float h = acc1[mi][ni][r] + b1;
          h = 0.5f * h * (1.f + erff(h * 0.70710678118654752f));
          int gs = (g & ~7) | ((g & 7) ^ (row & 7));
          S1l[row * 128 + gs * 8 + (hcol & 7)] = f2bf(h);
        }
      }
    }
    __syncthreads();

    // ---- stage B2 = fw2t (256 rows) cols [c*128, c*128+128) ----
    {
#pragma unroll
      for (int it = 0; it < 16; ++it) {
        int G = it * 256 + tid;
        int row = G >> 4, g = G & 15;
        uint4 vv = *(const uint4*)(fw2t + (size_t)row * 1024 + c * 128 + g * 8);
        int gs = (g & ~7) | ((g & 7) ^ (row & 7));
        *(uint4*)(Bl + row * 128 + gs * 8) = vv;
      }
    }
    __syncthreads();

    // ---- G2: accO += S1 @ B2^T ; wave = rows wm*64..+64, cols wn*128..+128 --
#pragma unroll
    for (int ks = 0; ks < 4; ++ks) {
      bf16x8 af2[4], bf2[8];
      int gb = ks * 4 + (lane >> 4);
#pragma unroll
      for (int mi = 0; mi < 4; ++mi) {
        int row = wm * 64 + mi * 16 + (lane & 15);
        int gs = (gb & ~7) | ((gb & 7) ^ (row & 7));
        af2[mi] = *(const bf16x8*)&S1l[row * 128 + gs * 8];
      }
#pragma unroll
      for (int ni = 0; ni < 8; ++ni) {
        int n = wn * 128 + ni * 16 + (lane & 15);
        int gs = (gb & ~7) | ((gb & 7) ^ (n & 7));
        bf2[ni] = *(const bf16x8*)&Bl[n * 128 + gs * 8];
      }
#pragma unroll
      for (int mi = 0; mi < 4; ++mi)
#pragma unroll
        for (int ni = 0; ni < 8; ++ni)
          accO[mi][ni] = __builtin_amdgcn_mfma_f32_16x16x32_bf16(af2[mi], bf2[ni], accO[mi][ni], 0, 0, 0);
    }
    __syncthreads();
  }

  // ---- epilogue: out = xmid + accO + fb2 ----
#pragma unroll
  for (int ni = 0; ni < 8; ++ni) {
    int col = wn * 128 + ni * 16 + (lane & 15);
    float b2 = fb2[col];
#pragma unroll
    for (int mi = 0; mi < 4; ++mi) {
#pragma unroll
      for (int r = 0; r < 4; ++r) {
        long row = rowBase + wm * 64 + mi * 16 + (lane >> 4) * 4 + r;
        size_t oi = (size_t)row * 256 + col;
        out[oi] = xmid[oi] + accO[mi][ni][r] + b2;
      }
    }
  }
}

// ---------------------------------------------------------------- launch ----
extern "C" void kernel_launch(void* const* d_in, const int* in_sizes, int n_in,
                              void* d_out, int out_size, void* d_ws, size_t ws_size,
                              hipStream_t stream) {
  const float* x1 = (const float*)d_in[0];
  const float* x2 = (const float*)d_in[1];
  const float* x3 = (const float*)d_in[2];
  const float* amask = (const float*)d_in[3];
  const float* g1 = (const float*)d_in[4];
  const float* bb1 = (const float*)d_in[5];
  const float* wq = (const float*)d_in[6];
  const float* bq = (const float*)d_in[7];
  const float* wk = (const float*)d_in[8];
  const float* bk = (const float*)d_in[9];
  const float* wv = (const float*)d_in[10];
  const float* bv = (const float*)d_in[11];
  const float* rel = (const float*)d_in[12];
  const float* wp = (const float*)d_in[13];
  const float* bp = (const float*)d_in[14];
  const float* g2 = (const float*)d_in[15];
  const float* bb2 = (const float*)d_in[16];
  const float* fw1 = (const float*)d_in[17];
  const float* fb1 = (const float*)d_in[18];
  const float* fw2 = (const float*)d_in[19];
  const float* fb2 = (const float*)d_in[20];

  char* wsb = (char*)d_ws;
  const size_t S = (size_t)50176 * 256 * 2;  // one bf16 token-matrix slot
  u16* xw1 = (u16*)(wsb + 0 * S);
  u16* xw2 = (u16*)(wsb + 1 * S);
  u16* xw3 = (u16*)(wsb + 2 * S);
  u16* qb = (u16*)(wsb + 3 * S);
  u16* kbuf = (u16*)(wsb + 4 * S);
  u16* vbuf = (u16*)(wsb + 5 * S);
  u16* attn_o = xw1;                    // reuse slot 0 (xw1 dead after QKV)
  float* x_mid = (float*)(wsb + 1 * S); // slots 1-2 (xw2/xw3 dead)
  u16* wqt = (u16*)(wsb + 6 * S);
  u16* wkt = wqt + 65536;
  u16* wvt = wkt + 65536;
  u16* wpt = wvt + 65536;
  u16* fw1t = wpt + 65536;
  u16* fw2t = fw1t + 262144;
  float* Bp = (float*)(fw2t + 262144);  // attn bias table (8.4 MB)

  static bool attr_set = false;
  (void)attr_set;
  hipFuncSetAttribute((const void*)mlp_fused,
                      hipFuncAttributeMaxDynamicSharedMemorySize, 163840);

  bias_prep<<<dim3(512), 256, 0, stream>>>(rel, amask, Bp);

  tconv<<<dim3(256), 256, 0, stream>>>(wq, wqt, 256, 256);
  tconv<<<dim3(256), 256, 0, stream>>>(wk, wkt, 256, 256);
  tconv<<<dim3(256), 256, 0, stream>>>(wv, wvt, 256, 256);
  tconv<<<dim3(256), 256, 0, stream>>>(wp, wpt, 256, 256);
  tconv<<<dim3(1024), 256, 0, stream>>>(fw1, fw1t, 256, 1024);
  tconv<<<dim3(1024), 256, 0, stream>>>(fw2, fw2t, 1024, 256);

  ln1_win<<<dim3(12544), 256, 0, stream>>>(x1, x2, x3, g1, bb1, xw1, xw2, xw3);

  gemm_nt<0><<<dim3(392, 2), 256, 0, stream>>>(xw1, wqt, bq, 0.17677669529663687f,
                                               50176, 256, 256, qb, nullptr);
  gemm_nt<0><<<dim3(392, 2), 256, 0, stream>>>(xw2, wkt, bk, 1.0f, 50176, 256, 256,
                                               kbuf, nullptr);
  gemm_nt<0><<<dim3(392, 2), 256, 0, stream>>>(xw3, wvt, bv, 1.0f, 50176, 256, 256,
                                               vbuf, nullptr);

  attn_mfma<<<dim3(8192), 64, 0, stream>>>(qb, kbuf, vbuf, Bp, attn_o);

  gemm_nt<2><<<dim3(392, 2), 256, 0, stream>>>(attn_o, wpt, bp, 1.0f, 50176, 256, 256,
                                               x_mid, x1);

  mlp_fused<<<dim3(392), 256, 163840, stream>>>(x_mid, g2, bb2, fw1t, fb1, fw2t,
                                                fb2, (float*)d_out);
}

// Round 4
// 388.349 us; speedup vs baseline: 1.4771x; 1.4771x over previous
//
#include <hip/hip_runtime.h>

typedef unsigned short u16;
typedef short bf16x8 __attribute__((ext_vector_type(8)));
typedef float f32x4 __attribute__((ext_vector_type(4)));

__device__ __forceinline__ u16 f2bf(float f) {
  union { float f; unsigned u; } x; x.f = f;
  unsigned r = x.u + 0x7FFFu + ((x.u >> 16) & 1u);
  return (u16)(r >> 16);
}

// ---------------------------------------------------------------- weights ---
// out[n*K + k] = bf16(in[k*N + n])   (K x N fp32  ->  N x K bf16)
__global__ void tconv(const float* __restrict__ in, u16* __restrict__ out, int K, int N) {
  int idx = blockIdx.x * 256 + threadIdx.x;
  if (idx >= K * N) return;
  int n = idx / K, k2 = idx - n * K;
  out[idx] = f2bf(in[(size_t)k2 * N + n]);
}

// ------------------------------------------------------- LN1+shift+window ---
__global__ __launch_bounds__(256)
void ln1_win(const float* __restrict__ x1, const float* __restrict__ x2,
             const float* __restrict__ x3, const float* __restrict__ g,
             const float* __restrict__ bb, u16* __restrict__ o1,
             u16* __restrict__ o2, u16* __restrict__ o3) {
  const int t = blockIdx.x * 4 + (threadIdx.x >> 6);
  const int lane = threadIdx.x & 63;
  const int win = t / 49, i = t - win * 49;
  const int b = win >> 6, wi = win & 63;
  const int ih = i / 7, iw = i - ih * 7;
  int h2 = (wi >> 3) * 7 + ih + 3; if (h2 >= 56) h2 -= 56;
  int w2 = (wi & 7) * 7 + iw + 3; if (w2 >= 56) w2 -= 56;
  const size_t src = ((size_t)b * 3136 + (size_t)h2 * 56 + w2) * 256 + lane * 4;
  const size_t dst = (size_t)t * 256 + lane * 4;
  const float4 gv = *(const float4*)(g + lane * 4);
  const float4 bv = *(const float4*)(bb + lane * 4);
  const float* xs[3] = {x1, x2, x3};
  u16* os[3] = {o1, o2, o3};
#pragma unroll
  for (int s = 0; s < 3; ++s) {
    float4 v = *(const float4*)(xs[s] + src);
    float sm = v.x + v.y + v.z + v.w;
    float s2 = v.x * v.x + v.y * v.y + v.z * v.z + v.w * v.w;
#pragma unroll
    for (int off = 32; off > 0; off >>= 1) {
      sm += __shfl_down(sm, off);
      s2 += __shfl_down(s2, off);
    }
    sm = __shfl(sm, 0); s2 = __shfl(s2, 0);
    float mean = sm * (1.f / 256.f);
    float rstd = rsqrtf(s2 * (1.f / 256.f) - mean * mean + 1e-5f);
    ushort4 o;
    o.x = f2bf((v.x - mean) * rstd * gv.x + bv.x);
    o.y = f2bf((v.y - mean) * rstd * gv.y + bv.y);
    o.z = f2bf((v.z - mean) * rstd * gv.z + bv.z);
    o.w = f2bf((v.w - mean) * rstd * gv.w + bv.w);
    *(ushort4*)(os[s] + dst) = o;
  }
}

// ------------------------------------------------------------------- LN2 ----
__global__ __launch_bounds__(256)
void ln2_k(const float* __restrict__ x, const float* __restrict__ g,
           const float* __restrict__ bb, u16* __restrict__ o) {
  const int t = blockIdx.x * 4 + (threadIdx.x >> 6);
  const int lane = threadIdx.x & 63;
  const size_t off = (size_t)t * 256 + lane * 4;
  const float4 gv = *(const float4*)(g + lane * 4);
  const float4 bv = *(const float4*)(bb + lane * 4);
  float4 v = *(const float4*)(x + off);
  float sm = v.x + v.y + v.z + v.w;
  float s2 = v.x * v.x + v.y * v.y + v.z * v.z + v.w * v.w;
#pragma unroll
  for (int d = 32; d > 0; d >>= 1) {
    sm += __shfl_down(sm, d);
    s2 += __shfl_down(s2, d);
  }
  sm = __shfl(sm, 0); s2 = __shfl(s2, 0);
  float mean = sm * (1.f / 256.f);
  float rstd = rsqrtf(s2 * (1.f / 256.f) - mean * mean + 1e-5f);
  ushort4 ov;
  ov.x = f2bf((v.x - mean) * rstd * gv.x + bv.x);
  ov.y = f2bf((v.y - mean) * rstd * gv.y + bv.y);
  ov.z = f2bf((v.z - mean) * rstd * gv.z + bv.z);
  ov.w = f2bf((v.w - mean) * rstd * gv.w + bv.w);
  *(ushort4*)(o + off) = ov;
}

// ---------------------------------------------------- K=256 GEMM, A-in-regs -
// C = A(Mx256 bf16) @ Bt^T(Nx256 bf16).  Block = 128 rows x full N sweep.
// A fragments in registers (read once); B in 64-col LDS chunks, dbuf.
// EPI 0: out bf16 = alpha*(acc+bias)        (Q/K/V)
// EPI 1: out bf16 = gelu(acc+bias)          (MLP1)
// EPI 2: out fp32 scatter + residual        (proj + win_rev + unshift)
template <int EPI>
__global__ __launch_bounds__(256, 2)
void gemm_k256(const u16* __restrict__ A, const u16* __restrict__ Bt,
               const float* __restrict__ bias, float alpha, int NC, int N,
               void* __restrict__ out_, const float* __restrict__ res) {
  __shared__ u16 Bl[2][64 * 256];
  const int tid = threadIdx.x, lane = tid & 63, wave = tid >> 6;
  const long rowBase = (long)blockIdx.x * 128;
  const int wrow = wave * 32;

  // A fragments: 2 m-tiles x 8 k-steps, straight from global (once)
  bf16x8 af[2][8];
#pragma unroll
  for (int mt = 0; mt < 2; ++mt)
#pragma unroll
    for (int ks = 0; ks < 8; ++ks)
      af[mt][ks] = *(const bf16x8*)(A + (size_t)(rowBase + wrow + mt * 16 + (lane & 15)) * 256 +
                                    ks * 32 + (lane >> 4) * 8);

  // scatter bases for EPI2 (rows fixed per thread across chunks)
  size_t obase[2][4];
  if constexpr (EPI == 2) {
#pragma unroll
    for (int mt = 0; mt < 2; ++mt)
#pragma unroll
      for (int r = 0; r < 4; ++r) {
        long row = rowBase + wrow + mt * 16 + (lane >> 4) * 4 + r;
        int win = (int)(row / 49), i = (int)(row - (long)win * 49);
        int b = win >> 6, wi = win & 63;
        int ih = i / 7, iw = i - ih * 7;
        int h2 = (wi >> 3) * 7 + ih + 3; if (h2 >= 56) h2 -= 56;
        int w2 = (wi & 7) * 7 + iw + 3; if (w2 >= 56) w2 -= 56;
        obase[mt][r] = ((size_t)b * 3136 + (size_t)h2 * 56 + w2) * 256;
      }
  }

  auto stageB = [&](u16* dst, int c) {
    const u16* src = Bt + (size_t)c * 64 * 256;
#pragma unroll
    for (int it = 0; it < 8; ++it) {
      int G = it * 256 + tid;  // 2048 granules = 64 rows x 32
      int r = G >> 5, g = G & 31;
      uint4 vv = *(const uint4*)(src + r * 256 + g * 8);
      int gs = (g & ~7) | ((g & 7) ^ (r & 7));
      *(uint4*)(dst + r * 256 + gs * 8) = vv;
    }
  };

  stageB(Bl[0], 0);

  for (int c = 0; c < NC; ++c) {
    __syncthreads();
    if (c + 1 < NC) stageB(Bl[(c + 1) & 1], c + 1);
    const u16* Bc = Bl[c & 1];

    f32x4 acc[2][4] = {};
#pragma unroll
    for (int ks = 0; ks < 8; ++ks) {
      bf16x8 bfv[4];
      int g = ks * 4 + (lane >> 4);
#pragma unroll
      for (int nt = 0; nt < 4; ++nt) {
        int r = nt * 16 + (lane & 15);
        int gs = (g & ~7) | ((g & 7) ^ (r & 7));
        bfv[nt] = *(const bf16x8*)&Bc[r * 256 + gs * 8];
      }
#pragma unroll
      for (int mt = 0; mt < 2; ++mt)
#pragma unroll
        for (int nt = 0; nt < 4; ++nt)
          acc[mt][nt] = __builtin_amdgcn_mfma_f32_16x16x32_bf16(af[mt][ks], bfv[nt], acc[mt][nt], 0, 0, 0);
    }

    if constexpr (EPI == 2) {
      float* out = (float*)out_;
#pragma unroll
      for (int mt = 0; mt < 2; ++mt)
#pragma unroll
        for (int r = 0; r < 4; ++r) {
          size_t ob = obase[mt][r];
#pragma unroll
          for (int nt = 0; nt < 4; ++nt) {
            int col = c * 64 + nt * 16 + (lane & 15);
            out[ob + col] = res[ob + col] + acc[mt][nt][r] + bias[col];
          }
        }
    } else {
      u16* out = (u16*)out_;
#pragma unroll
      for (int mt = 0; mt < 2; ++mt)
#pragma unroll
        for (int r = 0; r < 4; ++r) {
          size_t rowoff = (size_t)(rowBase + wrow + mt * 16 + (lane >> 4) * 4 + r) * N;
#pragma unroll
          for (int nt = 0; nt < 4; ++nt) {
            int col = c * 64 + nt * 16 + (lane & 15);
            float vv = acc[mt][nt][r] + bias[col];
            if constexpr (EPI == 0) vv *= alpha;
            else vv = 0.5f * vv * (1.f + erff(vv * 0.70710678118654752f));
            out[rowoff + col] = f2bf(vv);
          }
        }
    }
  }
}

// -------------------------------------------- K-loop GEMM (MLP2, K=1024) ----
#define BM 128
#define BN 128
#define BK 64

template <int EPI>
__global__ __launch_bounds__(256, 2)
void gemm_nt(const u16* __restrict__ A, const u16* __restrict__ Bt,
             const float* __restrict__ bias, int M, int N, int K,
             void* __restrict__ out_, const float* __restrict__ res) {
  __shared__ u16 As[2][BM * BK];
  __shared__ u16 Bs[2][BN * BK];
  const int tid = threadIdx.x;
  const int lane = tid & 63;
  const int wave = tid >> 6;
  const int wm = wave >> 1, wn = wave & 1;
  const long tM = (long)blockIdx.x * BM, tN = (long)blockIdx.y * BN;

  f32x4 acc[4][4] = {};

  auto stage = [&](u16* dst, const u16* src, long rowBase, int ld, int kOff) {
#pragma unroll
    for (int it = 0; it < 4; ++it) {
      int gi = it * 256 + tid;
      int row = gi >> 3, gl = gi & 7;
      int gs = gl ^ (row & 7);
      uint4 vv = *(const uint4*)(src + (size_t)(rowBase + row) * ld + kOff + gs * 8);
      *(uint4*)(dst + row * BK + gl * 8) = vv;
    }
  };

  stage(As[0], A, tM, K, 0);
  stage(Bs[0], Bt, tN, K, 0);
  __syncthreads();

  const int nkt = K / BK;
  for (int kt = 0; kt < nkt; ++kt) {
    const int cur = kt & 1;
    if (kt + 1 < nkt) {
      stage(As[cur ^ 1], A, tM, K, (kt + 1) * BK);
      stage(Bs[cur ^ 1], Bt, tN, K, (kt + 1) * BK);
    }
#pragma unroll
    for (int kk = 0; kk < BK; kk += 32) {
      bf16x8 af[4], bfv[4];
#pragma unroll
      for (int m = 0; m < 4; ++m) {
        int row = wm * 64 + m * 16 + (lane & 15);
        int g = (kk >> 3) + (lane >> 4);
        af[m] = *(const bf16x8*)&As[cur][row * BK + ((g ^ (row & 7)) << 3)];
      }
#pragma unroll
      for (int n = 0; n < 4; ++n) {
        int col = wn * 64 + n * 16 + (lane & 15);
        int g = (kk >> 3) + (lane >> 4);
        bfv[n] = *(const bf16x8*)&Bs[cur][col * BK + ((g ^ (col & 7)) << 3)];
      }
#pragma unroll
      for (int m = 0; m < 4; ++m)
#pragma unroll
        for (int n = 0; n < 4; ++n)
          acc[m][n] = __builtin_amdgcn_mfma_f32_16x16x32_bf16(af[m], bfv[n], acc[m][n], 0, 0, 0);
    }
    __syncthreads();
  }

#pragma unroll
  for (int m = 0; m < 4; ++m) {
#pragma unroll
    for (int r = 0; r < 4; ++r) {
      const long row = tM + wm * 64 + m * 16 + (lane >> 4) * 4 + r;
      float* out = (float*)out_;
#pragma unroll
      for (int n = 0; n < 4; ++n) {
        int col = (int)tN + wn * 64 + n * 16 + (lane & 15);
        size_t oi = (size_t)row * N + col;
        out[oi] = res[oi] + acc[m][n][r] + bias[col];
      }
    }
  }
}

// ------------------------------------------------- combined attn bias prep --
__global__ __launch_bounds__(256)
void bias_prep(const float* __restrict__ rel, const float* __restrict__ mask,
               float* __restrict__ Bp) {
  const int blk = blockIdx.x;  // 0..511
  const int wi = blk >> 3, h = blk & 7;
  const float* mrow = mask + (size_t)wi * 2401;
  float* o = Bp + (size_t)blk * 4096;
#pragma unroll
  for (int e = 0; e < 16; ++e) {
    int pos = e * 256 + threadIdx.x;
    int r = pos & 3, lane = (pos >> 2) & 63, mini = pos >> 8;
    int mi = mini >> 2, ni = mini & 3;
    int row = mi * 16 + (lane >> 4) * 4 + r;
    int col = ni * 16 + (lane & 15);
    float val;
    if (col >= 49) val = -1e30f;
    else if (row >= 49) val = 0.f;
    else {
      int idx = (row / 7 - col / 7 + 6) * 13 + (row % 7 - col % 7 + 6);
      val = rel[idx * 8 + h] + mrow[row * 49 + col];
    }
    o[pos] = val;
  }
}

// ------------------------------------------------------- MFMA attention -----
__global__ __launch_bounds__(64)
void attn_mfma(const u16* __restrict__ q, const u16* __restrict__ k,
               const u16* __restrict__ v, const float* __restrict__ Bp,
               u16* __restrict__ out) {
  __shared__ u16 Pl[64 * 64];
  __shared__ u16 VT[32 * 64];
  const int lane = threadIdx.x;
  const int unit = blockIdx.x;
  const int win = unit >> 3, head = unit & 7;
  const size_t base = (size_t)win * 49 * 256 + head * 32;

  {
    const int key = lane;
    const u16* vp = v + base + (size_t)key * 256;
#pragma unroll
    for (int p = 0; p < 4; ++p) {
      bf16x8 vv = {};
      if (key < 49) vv = *(const bf16x8*)(vp + p * 8);
#pragma unroll
      for (int e = 0; e < 8; ++e) {
        int dim = p * 8 + e;
        int sw = (dim ^ (dim >> 3)) & 7;
        VT[dim * 64 + ((((key >> 3) ^ sw) << 3) | (key & 7))] = (u16)vv[e];
      }
    }
  }

  const f32x4* bp = (const f32x4*)(Bp + (size_t)((win & 63) * 8 + head) * 4096);
  f32x4 acc[4][4];
#pragma unroll
  for (int mi = 0; mi < 4; ++mi)
#pragma unroll
    for (int ni = 0; ni < 4; ++ni)
      acc[mi][ni] = bp[(mi * 4 + ni) * 64 + lane];

  bf16x8 qf[4], kf[4];
#pragma unroll
  for (int mi = 0; mi < 4; ++mi)
    qf[mi] = *(const bf16x8*)(q + base + (size_t)(mi * 16 + (lane & 15)) * 256 + (lane >> 4) * 8);
#pragma unroll
  for (int ni = 0; ni < 4; ++ni)
    kf[ni] = *(const bf16x8*)(k + base + (size_t)(ni * 16 + (lane & 15)) * 256 + (lane >> 4) * 8);

#pragma unroll
  for (int mi = 0; mi < 4; ++mi)
#pragma unroll
    for (int ni = 0; ni < 4; ++ni)
      acc[mi][ni] = __builtin_amdgcn_mfma_f32_16x16x32_bf16(qf[mi], kf[ni], acc[mi][ni], 0, 0, 0);

  float rinv[4][4];
#pragma unroll
  for (int mi = 0; mi < 4; ++mi) {
#pragma unroll
    for (int r = 0; r < 4; ++r) {
      float mx = fmaxf(fmaxf(acc[mi][0][r], acc[mi][1][r]),
                       fmaxf(acc[mi][2][r], acc[mi][3][r]));
#pragma unroll
      for (int off = 1; off < 16; off <<= 1) mx = fmaxf(mx, __shfl_xor(mx, off));
      float s = 0.f;
#pragma unroll
      for (int ni = 0; ni < 4; ++ni) {
        float e = __expf(acc[mi][ni][r] - mx);
        acc[mi][ni][r] = e;
        s += e;
      }
#pragma unroll
      for (int off = 1; off < 16; off <<= 1) s += __shfl_xor(s, off);
      rinv[mi][r] = 1.f / s;
    }
  }

#pragma unroll
  for (int mi = 0; mi < 4; ++mi)
#pragma unroll
    for (int ni = 0; ni < 4; ++ni)
#pragma unroll
      for (int r = 0; r < 4; ++r) {
        int row = mi * 16 + (lane >> 4) * 4 + r;
        int col = ni * 16 + (lane & 15);
        int sw = (row ^ (row >> 3)) & 7;
        Pl[row * 64 + ((((col >> 3) ^ sw) << 3) | (col & 7))] = f2bf(acc[mi][ni][r]);
      }

  f32x4 acc2[4][2] = {};
#pragma unroll
  for (int ks = 0; ks < 2; ++ks) {
    bf16x8 pa[4], vb[2];
#pragma unroll
    for (int mi = 0; mi < 4; ++mi) {
      int row = mi * 16 + (lane & 15);
      int sw = (row ^ (row >> 3)) & 7;
      pa[mi] = *(const bf16x8*)&Pl[row * 64 + (((ks * 4 + (lane >> 4)) ^ sw) << 3)];
    }
#pragma unroll
    for (int n2 = 0; n2 < 2; ++n2) {
      int dim = n2 * 16 + (lane & 15);
      int sw = (dim ^ (dim >> 3)) & 7;
      vb[n2] = *(const bf16x8*)&VT[dim * 64 + (((ks * 4 + (lane >> 4)) ^ sw) << 3)];
    }
#pragma unroll
    for (int mi = 0; mi < 4; ++mi)
#pragma unroll
      for (int n2 = 0; n2 < 2; ++n2)
        acc2[mi][n2] = __builtin_amdgcn_mfma_f32_16x16x32_bf16(pa[mi], vb[n2], acc2[mi][n2], 0, 0, 0);
  }

#pragma unroll
  for (int mi = 0; mi < 4; ++mi)
#pragma unroll
    for (int r = 0; r < 4; ++r) {
      int row = mi * 16 + (lane >> 4) * 4 + r;
      if (row < 49) {
        float rv = rinv[mi][r];
#pragma unroll
        for (int n2 = 0; n2 < 2; ++n2) {
          int col = n2 * 16 + (lane & 15);
          out[base + (size_t)row * 256 + col] = f2bf(acc2[mi][n2][r] * rv);
        }
      }
    }
}

// ---------------------------------------------------------------- launch ----
extern "C" void kernel_launch(void* const* d_in, const int* in_sizes, int n_in,
                              void* d_out, int out_size, void* d_ws, size_t ws_size,
                              hipStream_t stream) {
  const float* x1 = (const float*)d_in[0];
  const float* x2 = (const float*)d_in[1];
  const float* x3 = (const float*)d_in[2];
  const float* amask = (const float*)d_in[3];
  const float* g1 = (const float*)d_in[4];
  const float* bb1 = (const float*)d_in[5];
  const float* wq = (const float*)d_in[6];
  const float* bq = (const float*)d_in[7];
  const float* wk = (const float*)d_in[8];
  const float* bk = (const float*)d_in[9];
  const float* wv = (const float*)d_in[10];
  const float* bv = (const float*)d_in[11];
  const float* rel = (const float*)d_in[12];
  const float* wp = (const float*)d_in[13];
  const float* bp = (const float*)d_in[14];
  const float* g2 = (const float*)d_in[15];
  const float* bb2 = (const float*)d_in[16];
  const float* fw1 = (const float*)d_in[17];
  const float* fb1 = (const float*)d_in[18];
  const float* fw2 = (const float*)d_in[19];
  const float* fb2 = (const float*)d_in[20];

  char* wsb = (char*)d_ws;
  const size_t S = (size_t)50176 * 256 * 2;  // one bf16 token-matrix slot
  u16* xw1 = (u16*)(wsb + 0 * S);
  u16* xw2 = (u16*)(wsb + 1 * S);
  u16* xw3 = (u16*)(wsb + 2 * S);
  u16* qb = (u16*)(wsb + 3 * S);
  u16* kbuf = (u16*)(wsb + 4 * S);
  u16* vbuf = (u16*)(wsb + 5 * S);
  u16* attn_o = xw1;                    // reuse slot 0 (xw1 dead after QKV)
  float* x_mid = (float*)(wsb + 1 * S); // slots 1-2 (xw2/xw3 dead)
  u16* x_ln2 = (u16*)(wsb + 3 * S);     // slot 3 (qb dead after attn)
  u16* wqt = (u16*)(wsb + 6 * S);
  u16* wkt = wqt + 65536;
  u16* wvt = wkt + 65536;
  u16* wpt = wvt + 65536;
  u16* fw1t = wpt + 65536;
  u16* fw2t = fw1t + 262144;
  float* Bp = (float*)(fw2t + 262144);  // attn bias (8.4MB)
  u16* h1 = (u16*)Bp;                   // 50176x1024 bf16 — lifetime disjoint from Bp

  bias_prep<<<dim3(512), 256, 0, stream>>>(rel, amask, Bp);

  tconv<<<dim3(256), 256, 0, stream>>>(wq, wqt, 256, 256);
  tconv<<<dim3(256), 256, 0, stream>>>(wk, wkt, 256, 256);
  tconv<<<dim3(256), 256, 0, stream>>>(wv, wvt, 256, 256);
  tconv<<<dim3(256), 256, 0, stream>>>(wp, wpt, 256, 256);
  tconv<<<dim3(1024), 256, 0, stream>>>(fw1, fw1t, 256, 1024);
  tconv<<<dim3(1024), 256, 0, stream>>>(fw2, fw2t, 1024, 256);

  ln1_win<<<dim3(12544), 256, 0, stream>>>(x1, x2, x3, g1, bb1, xw1, xw2, xw3);

  gemm_k256<0><<<dim3(392), 256, 0, stream>>>(xw1, wqt, bq, 0.17677669529663687f,
                                              4, 256, qb, nullptr);
  gemm_k256<0><<<dim3(392), 256, 0, stream>>>(xw2, wkt, bk, 1.0f, 4, 256, kbuf, nullptr);
  gemm_k256<0><<<dim3(392), 256, 0, stream>>>(xw3, wvt, bv, 1.0f, 4, 256, vbuf, nullptr);

  attn_mfma<<<dim3(8192), 64, 0, stream>>>(qb, kbuf, vbuf, Bp, attn_o);

  gemm_k256<2><<<dim3(392), 256, 0, stream>>>(attn_o, wpt, bp, 1.0f, 4, 256, x_mid, x1);

  ln2_k<<<dim3(12544), 256, 0, stream>>>(x_mid, g2, bb2, x_ln2);

  gemm_k256<1><<<dim3(392), 256, 0, stream>>>(x_ln2, fw1t, fb1, 1.0f, 16, 1024, h1, nullptr);

  gemm_nt<3><<<dim3(392, 2), 256, 0, stream>>>(h1, fw2t, fb2, 50176, 256, 1024,
                                               (float*)d_out, x_mid);
}

// Round 5
// 371.191 us; speedup vs baseline: 1.5454x; 1.0462x over previous
//
#include <hip/hip_runtime.h>

typedef unsigned short u16;
typedef short bf16x8 __attribute__((ext_vector_type(8)));
typedef float f32x4 __attribute__((ext_vector_type(4)));

__device__ __forceinline__ u16 f2bf(float f) {
  union { float f; unsigned u; } x; x.f = f;
  unsigned r = x.u + 0x7FFFu + ((x.u >> 16) & 1u);
  return (u16)(r >> 16);
}
__device__ __forceinline__ float bf_lo(unsigned u) {
  union { unsigned u; float f; } x; x.u = u << 16; return x.f;
}
__device__ __forceinline__ float bf_hi(unsigned u) {
  union { unsigned u; float f; } x; x.u = u & 0xFFFF0000u; return x.f;
}
__device__ __forceinline__ unsigned pack2bf(float a, float b) {
  return (unsigned)f2bf(a) | ((unsigned)f2bf(b) << 16);
}
__device__ __forceinline__ float gelu_f(float x) {
  float t = 0.7978845608028654f * x * (1.f + 0.044715f * x * x);
  return x / (1.f + __expf(-2.f * t));
}
// async global->LDS, 16B per lane; LDS dest must be linear (base + lane*16)
__device__ __forceinline__ void gll16(const void* g, void* l) {
  __builtin_amdgcn_global_load_lds(
      (const __attribute__((address_space(1))) unsigned int*)g,
      (__attribute__((address_space(3))) unsigned int*)l, 16, 0, 0);
}

// ---------------------------------------------------------------- weights ---
__global__ void tconv(const float* __restrict__ in, u16* __restrict__ out, int K, int N) {
  int idx = blockIdx.x * 256 + threadIdx.x;
  if (idx >= K * N) return;
  int n = idx / K, k2 = idx - n * K;
  out[idx] = f2bf(in[(size_t)k2 * N + n]);
}

// ------------------------------------------------------- LN1+shift+window ---
__global__ __launch_bounds__(256)
void ln1_win(const float* __restrict__ x1, const float* __restrict__ x2,
             const float* __restrict__ x3, const float* __restrict__ g,
             const float* __restrict__ bb, u16* __restrict__ o1,
             u16* __restrict__ o2, u16* __restrict__ o3) {
  const int t = blockIdx.x * 4 + (threadIdx.x >> 6);
  const int lane = threadIdx.x & 63;
  const int win = t / 49, i = t - win * 49;
  const int b = win >> 6, wi = win & 63;
  const int ih = i / 7, iw = i - ih * 7;
  int h2 = (wi >> 3) * 7 + ih + 3; if (h2 >= 56) h2 -= 56;
  int w2 = (wi & 7) * 7 + iw + 3; if (w2 >= 56) w2 -= 56;
  const size_t src = ((size_t)b * 3136 + (size_t)h2 * 56 + w2) * 256 + lane * 4;
  const size_t dst = (size_t)t * 256 + lane * 4;
  const float4 gv = *(const float4*)(g + lane * 4);
  const float4 bv = *(const float4*)(bb + lane * 4);
  const float* xs[3] = {x1, x2, x3};
  u16* os[3] = {o1, o2, o3};
#pragma unroll
  for (int s = 0; s < 3; ++s) {
    float4 v = *(const float4*)(xs[s] + src);
    float sm = v.x + v.y + v.z + v.w;
    float s2 = v.x * v.x + v.y * v.y + v.z * v.z + v.w * v.w;
#pragma unroll
    for (int off = 32; off > 0; off >>= 1) {
      sm += __shfl_down(sm, off);
      s2 += __shfl_down(s2, off);
    }
    sm = __shfl(sm, 0); s2 = __shfl(s2, 0);
    float mean = sm * (1.f / 256.f);
    float rstd = rsqrtf(s2 * (1.f / 256.f) - mean * mean + 1e-5f);
    ushort4 o;
    o.x = f2bf((v.x - mean) * rstd * gv.x + bv.x);
    o.y = f2bf((v.y - mean) * rstd * gv.y + bv.y);
    o.z = f2bf((v.z - mean) * rstd * gv.z + bv.z);
    o.w = f2bf((v.w - mean) * rstd * gv.w + bv.w);
    *(ushort4*)(os[s] + dst) = o;
  }
}

// ------------------------------------------------------------------- LN2 ----
__global__ __launch_bounds__(256)
void ln2_k(const float* __restrict__ x, const float* __restrict__ g,
           const float* __restrict__ bb, u16* __restrict__ o) {
  const int t = blockIdx.x * 4 + (threadIdx.x >> 6);
  const int lane = threadIdx.x & 63;
  const size_t off = (size_t)t * 256 + lane * 4;
  const float4 gv = *(const float4*)(g + lane * 4);
  const float4 bv = *(const float4*)(bb + lane * 4);
  float4 v = *(const float4*)(x + off);
  float sm = v.x + v.y + v.z + v.w;
  float s2 = v.x * v.x + v.y * v.y + v.z * v.z + v.w * v.w;
#pragma unroll
  for (int d = 32; d > 0; d >>= 1) {
    sm += __shfl_down(sm, d);
    s2 += __shfl_down(s2, d);
  }
  sm = __shfl(sm, 0); s2 = __shfl(s2, 0);
  float mean = sm * (1.f / 256.f);
  float rstd = rsqrtf(s2 * (1.f / 256.f) - mean * mean + 1e-5f);
  ushort4 ov;
  ov.x = f2bf((v.x - mean) * rstd * gv.x + bv.x);
  ov.y = f2bf((v.y - mean) * rstd * gv.y + bv.y);
  ov.z = f2bf((v.z - mean) * rstd * gv.z + bv.z);
  ov.w = f2bf((v.w - mean) * rstd * gv.w + bv.w);
  *(ushort4*)(o + off) = ov;
}

// ---------------------------------------------------- K=256 GEMM, A-in-regs -
// EPI 0: out bf16 = alpha*(acc+bias)   (Q/K/V)
// EPI 1: out bf16 = gelu(acc+bias)     (MLP1)
// EPI 2: out fp32 scatter + residual   (proj + win_rev + unshift)
// B staged via global_load_lds (linear LDS, pre-swizzled source); C restaged
// through a per-wave LDS slab into fully-coalesced 16B stores.
template <int EPI>
__global__ __launch_bounds__(256, 2)
void gemm_k256(const u16* __restrict__ A, const u16* __restrict__ Bt,
               const float* __restrict__ bias, float alpha, int NC, int N,
               void* __restrict__ out_, const float* __restrict__ res) {
  __shared__ __align__(16) u16 Bl[2][64 * 256];
  __shared__ __align__(16) u16 CSl[4][16 * 72];
  const int tid = threadIdx.x, lane = tid & 63, wave = tid >> 6;
  const int q = lane >> 4, m = lane & 15;
  const long rowBase = (long)blockIdx.x * 128;
  const int wrow = wave * 32;

  // A fragments: 2 m-tiles x 8 k-steps, read once from global
  bf16x8 af[2][8];
#pragma unroll
  for (int mt = 0; mt < 2; ++mt)
#pragma unroll
    for (int ks = 0; ks < 8; ++ks)
      af[mt][ks] = *(const bf16x8*)(A + (size_t)(rowBase + wrow + mt * 16 + m) * 256 +
                                    ks * 32 + q * 8);

  // scatter bases for EPI2 readback rows
  size_t obase2[2][2];
  if constexpr (EPI == 2) {
#pragma unroll
    for (int mt = 0; mt < 2; ++mt)
#pragma unroll
      for (int it = 0; it < 2; ++it) {
        long row = rowBase + wrow + mt * 16 + it * 8 + (lane >> 3);
        int win = (int)(row / 49), i = (int)(row - (long)win * 49);
        int b = win >> 6, wi = win & 63;
        int ih = i / 7, iw = i - ih * 7;
        int h2 = (wi >> 3) * 7 + ih + 3; if (h2 >= 56) h2 -= 56;
        int w2 = (wi & 7) * 7 + iw + 3; if (w2 >= 56) w2 -= 56;
        obase2[mt][it] = ((size_t)b * 3136 + (size_t)h2 * 56 + w2) * 256;
      }
  }

  auto stageB = [&](u16* dst, int c) {
#pragma unroll
    for (int it2 = 0; it2 < 8; ++it2) {
      int G = it2 * 256 + tid;
      int r = G >> 5, g = G & 31;
      int gs = (g & ~7) | ((g & 7) ^ (r & 7));
      gll16(Bt + (size_t)c * 16384 + r * 256 + gs * 8, dst + G * 8);
    }
  };

  stageB(Bl[0], 0);

  for (int c = 0; c < NC; ++c) {
    __syncthreads();  // drains vmcnt: staged buffer for c is complete
    if (c + 1 < NC) stageB(Bl[(c + 1) & 1], c + 1);
    const u16* Bc = Bl[c & 1];

    f32x4 acc[2][4] = {};
#pragma unroll
    for (int ks = 0; ks < 8; ++ks) {
      bf16x8 bfv[4];
      int g = ks * 4 + q;
#pragma unroll
      for (int nt = 0; nt < 4; ++nt) {
        int r = nt * 16 + m;
        int gs = (g & ~7) | ((g & 7) ^ (r & 7));
        bfv[nt] = *(const bf16x8*)&Bc[r * 256 + gs * 8];
      }
#pragma unroll
      for (int mt = 0; mt < 2; ++mt)
#pragma unroll
        for (int nt = 0; nt < 4; ++nt)
          acc[mt][nt] = __builtin_amdgcn_mfma_f32_16x16x32_bf16(af[mt][ks], bfv[nt], acc[mt][nt], 0, 0, 0);
    }

    // ---- epilogue: per-wave LDS restage -> coalesced 16B stores ----
    u16* slab = CSl[wave];
#pragma unroll
    for (int mt = 0; mt < 2; ++mt) {
#pragma unroll
      for (int nt = 0; nt < 4; ++nt) {
        float bvv = bias[c * 64 + nt * 16 + m];
        float v0 = acc[mt][nt][0] + bvv, v1 = acc[mt][nt][1] + bvv;
        float v2 = acc[mt][nt][2] + bvv, v3 = acc[mt][nt][3] + bvv;
        if constexpr (EPI == 0) { v0 *= alpha; v1 *= alpha; v2 *= alpha; v3 *= alpha; }
        if constexpr (EPI == 1) {
          v0 = gelu_f(v0); v1 = gelu_f(v1); v2 = gelu_f(v2); v3 = gelu_f(v3);
        }
        float p0 = __shfl_xor(v0, 1), p1 = __shfl_xor(v1, 1);
        float p2 = __shfl_xor(v2, 1), p3 = __shfl_xor(v3, 1);
        const int wi = nt * 8 + (m >> 1);
        unsigned w0, w1; int r0, r1;
        if ((m & 1) == 0) {
          w0 = pack2bf(v0, p0); w1 = pack2bf(v1, p1); r0 = 0; r1 = 1;
        } else {
          w0 = pack2bf(p2, v2); w1 = pack2bf(p3, v3); r0 = 2; r1 = 3;
        }
        *(unsigned*)&slab[(q * 4 + r0) * 72 + wi * 2] = w0;
        *(unsigned*)&slab[(q * 4 + r1) * 72 + wi * 2] = w1;
      }
#pragma unroll
      for (int it2 = 0; it2 < 2; ++it2) {
        int rr = it2 * 8 + (lane >> 3);
        int colg = lane & 7;
        uint4 y = *(const uint4*)&slab[rr * 72 + colg * 8];
        if constexpr (EPI == 2) {
          float* out = (float*)out_;
          size_t ob = obase2[mt][it2];
          int col = c * 64 + colg * 8;
          float4 ra = *(const float4*)(res + ob + col);
          float4 rb = *(const float4*)(res + ob + col + 4);
          float4 oa, obv;
          oa.x = ra.x + bf_lo(y.x); oa.y = ra.y + bf_hi(y.x);
          oa.z = ra.z + bf_lo(y.y); oa.w = ra.w + bf_hi(y.y);
          obv.x = rb.x + bf_lo(y.z); obv.y = rb.y + bf_hi(y.z);
          obv.z = rb.z + bf_lo(y.w); obv.w = rb.w + bf_hi(y.w);
          *(float4*)(out + ob + col) = oa;
          *(float4*)(out + ob + col + 4) = obv;
        } else {
          u16* out = (u16*)out_;
          long grow = rowBase + wrow + mt * 16 + rr;
          *(uint4*)(out + (size_t)grow * N + c * 64 + colg * 8) = y;
        }
      }
    }
  }
}

// -------------------------------------------- K-loop GEMM (MLP2, K=1024) ----
#define BM 128
#define BN 128
#define BK 64

__global__ __launch_bounds__(256, 2)
void gemm_nt3(const u16* __restrict__ A, const u16* __restrict__ Bt,
              const float* __restrict__ bias, int M, int N, int K,
              float* __restrict__ out, const float* __restrict__ res) {
  __shared__ __align__(16) u16 As[2][BM * BK];
  __shared__ __align__(16) u16 Bs[2][BN * BK];
  const int tid = threadIdx.x;
  const int lane = tid & 63;
  const int wave = tid >> 6;
  const int wm = wave >> 1, wn = wave & 1;
  const long tM = (long)blockIdx.x * BM, tN = (long)blockIdx.y * BN;

  f32x4 acc[4][4] = {};

  auto stage = [&](u16* dst, const u16* src, long rowBase, int ld, int kOff) {
#pragma unroll
    for (int it = 0; it < 4; ++it) {
      int gi = it * 256 + tid;
      int row = gi >> 3, gl = gi & 7;
      int gs = gl ^ (row & 7);
      gll16(src + (size_t)(rowBase + row) * ld + kOff + gs * 8, dst + gi * 8);
    }
  };

  stage(As[0], A, tM, K, 0);
  stage(Bs[0], Bt, tN, K, 0);
  __syncthreads();

  const int nkt = K / BK;
  for (int kt = 0; kt < nkt; ++kt) {
    const int cur = kt & 1;
    if (kt + 1 < nkt) {
      stage(As[cur ^ 1], A, tM, K, (kt + 1) * BK);
      stage(Bs[cur ^ 1], Bt, tN, K, (kt + 1) * BK);
    }
#pragma unroll
    for (int kk = 0; kk < BK; kk += 32) {
      bf16x8 af[4], bfv[4];
#pragma unroll
      for (int m = 0; m < 4; ++m) {
        int row = wm * 64 + m * 16 + (lane & 15);
        int g = (kk >> 3) + (lane >> 4);
        af[m] = *(const bf16x8*)&As[cur][row * BK + ((g ^ (row & 7)) << 3)];
      }
#pragma unroll
      for (int n = 0; n < 4; ++n) {
        int col = wn * 64 + n * 16 + (lane & 15);
        int g = (kk >> 3) + (lane >> 4);
        bfv[n] = *(const bf16x8*)&Bs[cur][col * BK + ((g ^ (col & 7)) << 3)];
      }
#pragma unroll
      for (int m = 0; m < 4; ++m)
#pragma unroll
        for (int n = 0; n < 4; ++n)
          acc[m][n] = __builtin_amdgcn_mfma_f32_16x16x32_bf16(af[m], bfv[n], acc[m][n], 0, 0, 0);
    }
    __syncthreads();
  }

#pragma unroll
  for (int m = 0; m < 4; ++m) {
#pragma unroll
    for (int r = 0; r < 4; ++r) {
      const long row = tM + wm * 64 + m * 16 + (lane >> 4) * 4 + r;
#pragma unroll
      for (int n = 0; n < 4; ++n) {
        int col = (int)tN + wn * 64 + n * 16 + (lane & 15);
        size_t oi = (size_t)row * N + col;
        out[oi] = res[oi] + acc[m][n][r] + bias[col];
      }
    }
  }
}

// ------------------------------------------------- combined attn bias prep --
__global__ __launch_bounds__(256)
void bias_prep(const float* __restrict__ rel, const float* __restrict__ mask,
               float* __restrict__ Bp) {
  const int blk = blockIdx.x;  // 0..511
  const int wi = blk >> 3, h = blk & 7;
  const float* mrow = mask + (size_t)wi * 2401;
  float* o = Bp + (size_t)blk * 4096;
#pragma unroll
  for (int e = 0; e < 16; ++e) {
    int pos = e * 256 + threadIdx.x;
    int r = pos & 3, lane = (pos >> 2) & 63, mini = pos >> 8;
    int mi = mini >> 2, ni = mini & 3;
    int row = mi * 16 + (lane >> 4) * 4 + r;
    int col = ni * 16 + (lane & 15);
    float val;
    if (col >= 49) val = -1e30f;
    else if (row >= 49) val = 0.f;
    else {
      int idx = (row / 7 - col / 7 + 6) * 13 + (row % 7 - col % 7 + 6);
      val = rel[idx * 8 + h] + mrow[row * 49 + col];
    }
    o[pos] = val;
  }
}

// ------------------------------------------------------- MFMA attention -----
__global__ __launch_bounds__(64)
void attn_mfma(const u16* __restrict__ q, const u16* __restrict__ k,
               const u16* __restrict__ v, const float* __restrict__ Bp,
               u16* __restrict__ out) {
  __shared__ u16 Pl[64 * 64];
  __shared__ u16 VT[32 * 64];
  const int lane = threadIdx.x;
  const int unit = blockIdx.x;
  const int win = unit >> 3, head = unit & 7;
  const size_t base = (size_t)win * 49 * 256 + head * 32;

  {
    const int key = lane;
    const u16* vp = v + base + (size_t)key * 256;
#pragma unroll
    for (int p = 0; p < 4; ++p) {
      bf16x8 vv = {};
      if (key < 49) vv = *(const bf16x8*)(vp + p * 8);
#pragma unroll
      for (int e = 0; e < 8; ++e) {
        int dim = p * 8 + e;
        int sw = (dim ^ (dim >> 3)) & 7;
        VT[dim * 64 + ((((key >> 3) ^ sw) << 3) | (key & 7))] = (u16)vv[e];
      }
    }
  }

  const f32x4* bp = (const f32x4*)(Bp + (size_t)((win & 63) * 8 + head) * 4096);
  f32x4 acc[4][4];
#pragma unroll
  for (int mi = 0; mi < 4; ++mi)
#pragma unroll
    for (int ni = 0; ni < 4; ++ni)
      acc[mi][ni] = bp[(mi * 4 + ni) * 64 + lane];

  bf16x8 qf[4], kf[4];
#pragma unroll
  for (int mi = 0; mi < 4; ++mi)
    qf[mi] = *(const bf16x8*)(q + base + (size_t)(mi * 16 + (lane & 15)) * 256 + (lane >> 4) * 8);
#pragma unroll
  for (int ni = 0; ni < 4; ++ni)
    kf[ni] = *(const bf16x8*)(k + base + (size_t)(ni * 16 + (lane & 15)) * 256 + (lane >> 4) * 8);

#pragma unroll
  for (int mi = 0; mi < 4; ++mi)
#pragma unroll
    for (int ni = 0; ni < 4; ++ni)
      acc[mi][ni] = __builtin_amdgcn_mfma_f32_16x16x32_bf16(qf[mi], kf[ni], acc[mi][ni], 0, 0, 0);

  float rinv[4][4];
#pragma unroll
  for (int mi = 0; mi < 4; ++mi) {
#pragma unroll
    for (int r = 0; r < 4; ++r) {
      float mx = fmaxf(fmaxf(acc[mi][0][r], acc[mi][1][r]),
                       fmaxf(acc[mi][2][r], acc[mi][3][r]));
#pragma unroll
      for (int off = 1; off < 16; off <<= 1) mx = fmaxf(mx, __shfl_xor(mx, off));
      float s = 0.f;
#pragma unroll
      for (int ni = 0; ni < 4; ++ni) {
        float e = __expf(acc[mi][ni][r] - mx);
        acc[mi][ni][r] = e;
        s += e;
      }
#pragma unroll
      for (int off = 1; off < 16; off <<= 1) s += __shfl_xor(s, off);
      rinv[mi][r] = 1.f / s;
    }
  }

#pragma unroll
  for (int mi = 0; mi < 4; ++mi)
#pragma unroll
    for (int ni = 0; ni < 4; ++ni)
#pragma unroll
      for (int r = 0; r < 4; ++r) {
        int row = mi * 16 + (lane >> 4) * 4 + r;
        int col = ni * 16 + (lane & 15);
        int sw = (row ^ (row >> 3)) & 7;
        Pl[row * 64 + ((((col >> 3) ^ sw) << 3) | (col & 7))] = f2bf(acc[mi][ni][r]);
      }

  f32x4 acc2[4][2] = {};
#pragma unroll
  for (int ks = 0; ks < 2; ++ks) {
    bf16x8 pa[4], vb[2];
#pragma unroll
    for (int mi = 0; mi < 4; ++mi) {
      int row = mi * 16 + (lane & 15);
      int sw = (row ^ (row >> 3)) & 7;
      pa[mi] = *(const bf16x8*)&Pl[row * 64 + (((ks * 4 + (lane >> 4)) ^ sw) << 3)];
    }
#pragma unroll
    for (int n2 = 0; n2 < 2; ++n2) {
      int dim = n2 * 16 + (lane & 15);
      int sw = (dim ^ (dim >> 3)) & 7;
      vb[n2] = *(const bf16x8*)&VT[dim * 64 + (((ks * 4 + (lane >> 4)) ^ sw) << 3)];
    }
#pragma unroll
    for (int mi = 0; mi < 4; ++mi)
#pragma unroll
      for (int n2 = 0; n2 < 2; ++n2)
        acc2[mi][n2] = __builtin_amdgcn_mfma_f32_16x16x32_bf16(pa[mi], vb[n2], acc2[mi][n2], 0, 0, 0);
  }

#pragma unroll
  for (int mi = 0; mi < 4; ++mi)
#pragma unroll
    for (int r = 0; r < 4; ++r) {
      int row = mi * 16 + (lane >> 4) * 4 + r;
      if (row < 49) {
        float rv = rinv[mi][r];
#pragma unroll
        for (int n2 = 0; n2 < 2; ++n2) {
          int col = n2 * 16 + (lane & 15);
          out[base + (size_t)row * 256 + col] = f2bf(acc2[mi][n2][r] * rv);
        }
      }
    }
}

// ---------------------------------------------------------------- launch ----
extern "C" void kernel_launch(void* const* d_in, const int* in_sizes, int n_in,
                              void* d_out, int out_size, void* d_ws, size_t ws_size,
                              hipStream_t stream) {
  const float* x1 = (const float*)d_in[0];
  const float* x2 = (const float*)d_in[1];
  const float* x3 = (const float*)d_in[2];
  const float* amask = (const float*)d_in[3];
  const float* g1 = (const float*)d_in[4];
  const float* bb1 = (const float*)d_in[5];
  const float* wq = (const float*)d_in[6];
  const float* bq = (const float*)d_in[7];
  const float* wk = (const float*)d_in[8];
  const float* bk = (const float*)d_in[9];
  const float* wv = (const float*)d_in[10];
  const float* bv = (const float*)d_in[11];
  const float* rel = (const float*)d_in[12];
  const float* wp = (const float*)d_in[13];
  const float* bp = (const float*)d_in[14];
  const float* g2 = (const float*)d_in[15];
  const float* bb2 = (const float*)d_in[16];
  const float* fw1 = (const float*)d_in[17];
  const float* fb1 = (const float*)d_in[18];
  const float* fw2 = (const float*)d_in[19];
  const float* fb2 = (const float*)d_in[20];

  char* wsb = (char*)d_ws;
  const size_t S = (size_t)50176 * 256 * 2;  // one bf16 token-matrix slot
  u16* xw1 = (u16*)(wsb + 0 * S);
  u16* xw2 = (u16*)(wsb + 1 * S);
  u16* xw3 = (u16*)(wsb + 2 * S);
  u16* qb = (u16*)(wsb + 3 * S);
  u16* kbuf = (u16*)(wsb + 4 * S);
  u16* vbuf = (u16*)(wsb + 5 * S);
  u16* attn_o = xw1;                    // reuse slot 0 (xw1 dead after QKV)
  float* x_mid = (float*)(wsb + 1 * S); // slots 1-2 (xw2/xw3 dead)
  u16* x_ln2 = (u16*)(wsb + 3 * S);     // slot 3 (qb dead after attn)
  u16* wqt = (u16*)(wsb + 6 * S);
  u16* wkt = wqt + 65536;
  u16* wvt = wkt + 65536;
  u16* wpt = wvt + 65536;
  u16* fw1t = wpt + 65536;
  u16* fw2t = fw1t + 262144;
  float* Bp = (float*)(fw2t + 262144);  // attn bias (8.4MB)
  u16* h1 = (u16*)Bp;                   // 50176x1024 bf16 — lifetime disjoint from Bp

  bias_prep<<<dim3(512), 256, 0, stream>>>(rel, amask, Bp);

  tconv<<<dim3(256), 256, 0, stream>>>(wq, wqt, 256, 256);
  tconv<<<dim3(256), 256, 0, stream>>>(wk, wkt, 256, 256);
  tconv<<<dim3(256), 256, 0, stream>>>(wv, wvt, 256, 256);
  tconv<<<dim3(256), 256, 0, stream>>>(wp, wpt, 256, 256);
  tconv<<<dim3(1024), 256, 0, stream>>>(fw1, fw1t, 256, 1024);
  tconv<<<dim3(1024), 256, 0, stream>>>(fw2, fw2t, 1024, 256);

  ln1_win<<<dim3(12544), 256, 0, stream>>>(x1, x2, x3, g1, bb1, xw1, xw2, xw3);

  gemm_k256<0><<<dim3(392), 256, 0, stream>>>(xw1, wqt, bq, 0.17677669529663687f,
                                              4, 256, qb, nullptr);
  gemm_k256<0><<<dim3(392), 256, 0, stream>>>(xw2, wkt, bk, 1.0f, 4, 256, kbuf, nullptr);
  gemm_k256<0><<<dim3(392), 256, 0, stream>>>(xw3, wvt, bv, 1.0f, 4, 256, vbuf, nullptr);

  attn_mfma<<<dim3(8192), 64, 0, stream>>>(qb, kbuf, vbuf, Bp, attn_o);

  gemm_k256<2><<<dim3(392), 256, 0, stream>>>(attn_o, wpt, bp, 1.0f, 4, 256, x_mid, x1);

  ln2_k<<<dim3(12544), 256, 0, stream>>>(x_mid, g2, bb2, x_ln2);

  gemm_k256<1><<<dim3(392), 256, 0, stream>>>(x_ln2, fw1t, fb1, 1.0f, 16, 1024, h1, nullptr);

  gemm_nt3<<<dim3(392, 2), 256, 0, stream>>>(h1, fw2t, fb2, 50176, 256, 1024,
                                             (float*)d_out, x_mid);
}